// Round 2
// baseline (14458.177 us; speedup 1.0000x reference)
//
#include <hip/hip_runtime.h>
#include <hip/hip_bf16.h>
#include <math.h>

// Problem constants
#define BB 8
#define SS 1024
#define DD 512
#define HH 8
#define FF 2048
#define LL 6
#define HD 64
#define MM (BB * SS)      // 8192 rows
#define EPS 1e-6f

// ---------------------------------------------------------------------------
// Kernel 1: embedding gather * sqrt(D) + sinusoidal positional encoding
// ---------------------------------------------------------------------------
__global__ __launch_bounds__(256) void embed_pe_kernel(
    const int* __restrict__ tokens, const float* __restrict__ emb,
    float* __restrict__ x)
{
    int idx = blockIdx.x * 256 + threadIdx.x;   // over B*S*D = 4M
    int d  = idx & (DD - 1);
    int bs = idx >> 9;                           // D = 512 = 2^9
    int s  = bs & (SS - 1);
    int tok = tokens[bs];
    float val = emb[(size_t)tok * DD + d] * 22.62741699796952f;  // sqrt(512)
    // pe: even d -> sin(pos*div_i), odd d -> cos(pos*div_i), div_i uses 2*(d/2)
    int i2 = d & ~1;
    float freq = expf((float)i2 * -0.017988946039015984f);  // -ln(10000)/512
    float ang = (float)s * freq;
    val += (d & 1) ? cosf(ang) : sinf(ang);
    x[idx] = val;
}

// ---------------------------------------------------------------------------
// Kernel 2: LayerNorm (reference semantics: unbiased std, eps added to std,
// scalar alpha/bias). One block (256 threads) per row of 512.
// ---------------------------------------------------------------------------
__global__ __launch_bounds__(256) void ln_kernel(
    const float* __restrict__ x, float* __restrict__ y,
    const float* __restrict__ alpha_p, const float* __restrict__ beta_p)
{
    int row = blockIdx.x;
    const float* xr = x + (size_t)row * DD;
    int t = threadIdx.x;
    float v0 = xr[t];
    float v1 = xr[t + 256];

    __shared__ float red[8];
    // --- mean ---
    float s = v0 + v1;
    #pragma unroll
    for (int o = 32; o >= 1; o >>= 1) s += __shfl_xor(s, o, 64);
    int wid = t >> 6;
    if ((t & 63) == 0) red[wid] = s;
    __syncthreads();
    float mean = (red[0] + red[1] + red[2] + red[3]) * (1.0f / 512.0f);

    // --- unbiased variance ---
    float d0 = v0 - mean, d1 = v1 - mean;
    float q = d0 * d0 + d1 * d1;
    #pragma unroll
    for (int o = 32; o >= 1; o >>= 1) q += __shfl_xor(q, o, 64);
    if ((t & 63) == 0) red[4 + wid] = q;
    __syncthreads();
    float var = (red[4] + red[5] + red[6] + red[7]) * (1.0f / 511.0f);
    float stdv = sqrtf(var);

    float alpha = alpha_p[0], beta = beta_p[0];
    float inv = alpha / (stdv + EPS);
    float* yr = y + (size_t)row * DD;
    yr[t]       = d0 * inv + beta;
    yr[t + 256] = d1 * inv + beta;
}

// ---------------------------------------------------------------------------
// Kernel 3: fp32 tiled GEMM  C[M,N] = A[M,K] @ W[K,N] + bias[N]
//           (+ optional residual add, optional ReLU)
// 64x64 tile, BK=16, 256 threads, 4x4 micro-tile per thread.
// ---------------------------------------------------------------------------
template <bool RELU, bool RES>
__global__ __launch_bounds__(256) void gemm_kernel(
    const float* __restrict__ A, const float* __restrict__ W,
    const float* __restrict__ bias, const float* __restrict__ R,
    float* __restrict__ C, int M, int N, int K)
{
    __shared__ float As[16][64];   // [k][m]
    __shared__ float Ws[16][64];   // [k][n]

    int t  = threadIdx.x;
    int tx = t & 15, ty = t >> 4;
    int m0 = blockIdx.y * 64, n0 = blockIdx.x * 64;

    float acc[4][4] = {};

    for (int k0 = 0; k0 < K; k0 += 16) {
        // load A tile 64x16: thread loads 4 consecutive k at one row
        {
            int m  = t >> 2;           // 0..63
            int kk = (t & 3) * 4;      // 0,4,8,12
            const float4 av = *(const float4*)(A + (size_t)(m0 + m) * K + k0 + kk);
            As[kk + 0][m] = av.x; As[kk + 1][m] = av.y;
            As[kk + 2][m] = av.z; As[kk + 3][m] = av.w;
        }
        // load W tile 16x64: thread loads 4 consecutive n in one k-row
        {
            int kw = t >> 4;           // 0..15
            int n  = (t & 15) * 4;     // 0..60
            const float4 wv = *(const float4*)(W + (size_t)(k0 + kw) * N + n0 + n);
            Ws[kw][n + 0] = wv.x; Ws[kw][n + 1] = wv.y;
            Ws[kw][n + 2] = wv.z; Ws[kw][n + 3] = wv.w;
        }
        __syncthreads();
        #pragma unroll
        for (int kk = 0; kk < 16; ++kk) {
            float a[4], b[4];
            #pragma unroll
            for (int i = 0; i < 4; ++i) a[i] = As[kk][ty * 4 + i];
            #pragma unroll
            for (int j = 0; j < 4; ++j) b[j] = Ws[kk][tx * 4 + j];
            #pragma unroll
            for (int i = 0; i < 4; ++i)
                #pragma unroll
                for (int j = 0; j < 4; ++j)
                    acc[i][j] = fmaf(a[i], b[j], acc[i][j]);
        }
        __syncthreads();
    }

    #pragma unroll
    for (int i = 0; i < 4; ++i) {
        int m = m0 + ty * 4 + i;
        #pragma unroll
        for (int j = 0; j < 4; ++j) {
            int n = n0 + tx * 4 + j;
            float c = acc[i][j] + bias[n];
            if (RES)  c += R[(size_t)m * N + n];
            if (RELU) c = fmaxf(c, 0.0f);
            C[(size_t)m * N + n] = c;
        }
    }
}

// ---------------------------------------------------------------------------
// Kernel 4: flash-style attention. One block = one (b,h) and 64 q-rows.
// 256 threads: thread t -> q-row r = t/4, group g = t%4 owns 16 dims / 16 keys.
// Q is held in registers (64 fp32/thread, duplicated across the 4 group
// threads of a row) so LDS = K+V+P only (49,920 B < 64 KiB static limit).
// q,k,v layouts are [B,S,D] with head h at column offset h*64; o written the
// same way (heads already re-concatenated for the output projection).
// ---------------------------------------------------------------------------
__global__ __launch_bounds__(256) void attn_kernel(
    const float* __restrict__ q, const float* __restrict__ k,
    const float* __restrict__ v, const int* __restrict__ mask,
    float* __restrict__ o)
{
    __shared__ float Ks[64][65];
    __shared__ float Vs[64][65];
    __shared__ float Ps[64][65];

    int qt = blockIdx.x;               // q tile (0..15)
    int bh = blockIdx.y;               // 0..63
    int b = bh >> 3, h = bh & 7;
    int s0 = qt * 64;

    const float* kb = k + ((size_t)b * SS) * DD + h * HD;
    const float* vb = v + ((size_t)b * SS) * DD + h * HD;
    const int*   mb = mask + (size_t)b * SS;

    int t = threadIdx.x;
    int r = t >> 2;     // q row in tile
    int g = t & 3;      // group

    // Q row into registers (all 64 dims; 16x float4)
    float qd[64];
    {
        const float* qrow = q + ((size_t)b * SS + s0 + r) * DD + h * HD;
        #pragma unroll
        for (int i = 0; i < 16; ++i) {
            float4 qv = *(const float4*)(qrow + i * 4);
            qd[i * 4 + 0] = qv.x; qd[i * 4 + 1] = qv.y;
            qd[i * 4 + 2] = qv.z; qd[i * 4 + 3] = qv.w;
        }
    }

    float m_run = -INFINITY;
    float l_run = 0.0f;
    float acc[16];
    #pragma unroll
    for (int i = 0; i < 16; ++i) acc[i] = 0.0f;

    for (int kt = 0; kt < SS / 64; ++kt) {
        // load K,V tiles (each thread: 4 rows x 4 floats... 16 elems per array)
        #pragma unroll
        for (int i = 0; i < 16; ++i) {
            int l = t + i * 256;
            int row = l >> 6, dc = l & 63;
            Ks[row][dc] = kb[(size_t)(kt * 64 + row) * DD + dc];
            Vs[row][dc] = vb[(size_t)(kt * 64 + row) * DD + dc];
        }
        __syncthreads();

        // scores for the 16 keys owned by this thread
        float sc[16];
        float lmax = -INFINITY;
        #pragma unroll
        for (int jj = 0; jj < 16; ++jj) {
            int j = g * 16 + jj;
            float sdot = 0.0f;
            #pragma unroll
            for (int dd = 0; dd < 64; ++dd)
                sdot = fmaf(qd[dd], Ks[j][dd], sdot);
            sdot *= 0.125f;   // 1/sqrt(64)
            if (mb[kt * 64 + j] == 0) sdot = -1e9f;
            sc[jj] = sdot;
            lmax = fmaxf(lmax, sdot);
        }
        // reduce max across the 4 group-threads of this row
        lmax = fmaxf(lmax, __shfl_xor(lmax, 1, 64));
        lmax = fmaxf(lmax, __shfl_xor(lmax, 2, 64));
        float m_new = fmaxf(m_run, lmax);

        float scale_old = expf(m_run - m_new);   // 0 on first iter (-inf)
        float psum = 0.0f;
        #pragma unroll
        for (int jj = 0; jj < 16; ++jj) {
            float p = expf(sc[jj] - m_new);
            Ps[r][g * 16 + jj] = p;
            psum += p;
        }
        psum += __shfl_xor(psum, 1, 64);
        psum += __shfl_xor(psum, 2, 64);

        l_run = l_run * scale_old + psum;
        #pragma unroll
        for (int i = 0; i < 16; ++i) acc[i] *= scale_old;
        m_run = m_new;
        __syncthreads();   // Ps visible

        // PV: accumulate 16 dims (g*16..g*16+15) over 64 keys
        #pragma unroll
        for (int j = 0; j < 64; ++j) {
            float p = Ps[r][j];
            #pragma unroll
            for (int dd = 0; dd < 16; ++dd)
                acc[dd] = fmaf(p, Vs[j][g * 16 + dd], acc[dd]);
        }
        __syncthreads();   // before next tile overwrites Ks/Vs/Ps
    }

    float invl = 1.0f / l_run;
    float* ob = o + ((size_t)b * SS + s0 + r) * DD + h * HD + g * 16;
    #pragma unroll
    for (int dd = 0; dd < 16; ++dd) ob[dd] = acc[dd] * invl;
}

// ---------------------------------------------------------------------------
// Host launcher
// ---------------------------------------------------------------------------
extern "C" void kernel_launch(void* const* d_in, const int* in_sizes, int n_in,
                              void* d_out, int out_size, void* d_ws, size_t ws_size,
                              hipStream_t stream)
{
    const int*   tokens = (const int*)  d_in[0];
    const int*   mask   = (const int*)  d_in[1];
    const float* emb    = (const float*)d_in[2];
    const float* Wq     = (const float*)d_in[3];
    const float* bq     = (const float*)d_in[4];
    const float* Wk     = (const float*)d_in[5];
    const float* bk     = (const float*)d_in[6];
    const float* Wv     = (const float*)d_in[7];
    const float* bv     = (const float*)d_in[8];
    const float* Wo     = (const float*)d_in[9];
    const float* bo     = (const float*)d_in[10];
    const float* W1     = (const float*)d_in[11];
    const float* b1     = (const float*)d_in[12];
    const float* W2     = (const float*)d_in[13];
    const float* b2     = (const float*)d_in[14];
    const float* ln_a1  = (const float*)d_in[15];
    const float* ln_b1  = (const float*)d_in[16];
    const float* ln_a2  = (const float*)d_in[17];
    const float* ln_b2  = (const float*)d_in[18];

    float* x  = (float*)d_out;                 // residual stream, in place
    float* ws = (float*)d_ws;
    const size_t ACT = (size_t)MM * DD;        // 4M floats
    float* h  = ws;                            // LN out / attn out
    float* qb = ws + ACT;
    float* kb = ws + 2 * ACT;
    float* vb = ws + 3 * ACT;
    float* ff = ws + ACT;                      // [8192,2048] overlaps q,k,v

    // x = emb[tokens]*sqrt(D) + PE
    embed_pe_kernel<<<(MM * DD) / 256, 256, 0, stream>>>(tokens, emb, x);

    dim3 gD(DD / 64, MM / 64);      // N=512 GEMMs
    dim3 gF(FF / 64, MM / 64);      // N=2048 GEMM

    for (int layer = 0; layer < LL; ++layer) {
        // --- attention sublayer ---
        ln_kernel<<<MM, 256, 0, stream>>>(x, h, ln_a1, ln_b1);
        gemm_kernel<false, false><<<gD, 256, 0, stream>>>(h, Wq, bq, nullptr, qb, MM, DD, DD);
        gemm_kernel<false, false><<<gD, 256, 0, stream>>>(h, Wk, bk, nullptr, kb, MM, DD, DD);
        gemm_kernel<false, false><<<gD, 256, 0, stream>>>(h, Wv, bv, nullptr, vb, MM, DD, DD);
        attn_kernel<<<dim3(SS / 64, BB * HH), 256, 0, stream>>>(qb, kb, vb, mask, h);
        gemm_kernel<false, true><<<gD, 256, 0, stream>>>(h, Wo, bo, x, x, MM, DD, DD);

        // --- feed-forward sublayer ---
        ln_kernel<<<MM, 256, 0, stream>>>(x, h, ln_a2, ln_b2);
        gemm_kernel<true, false><<<gF, 256, 0, stream>>>(h, W1, b1, nullptr, ff, MM, FF, DD);
        gemm_kernel<false, true><<<gD, 256, 0, stream>>>(ff, W2, b2, x, x, MM, DD, FF);
    }
}

// Round 4
// 1488.798 us; speedup vs baseline: 9.7113x; 9.7113x over previous
//
#include <hip/hip_runtime.h>
#include <hip/hip_bf16.h>
#include <math.h>

// Problem constants
#define BB 8
#define SS 1024
#define DD 512
#define HH 8
#define FF 2048
#define LL 6
#define HD 64
#define MM (BB * SS)      // 8192 rows
#define EPS 1e-6f

typedef __attribute__((ext_vector_type(8))) short bf16x8;
typedef __attribute__((ext_vector_type(4))) float f32x4;

typedef __attribute__((address_space(1))) const unsigned int g_u32;
typedef __attribute__((address_space(3))) unsigned int l_u32;

__device__ __forceinline__ short f2bf(float f) {
    union { float f; unsigned u; } c; c.f = f;
    unsigned u = c.u;
    u += 0x7fff + ((u >> 16) & 1);   // RNE
    return (short)(u >> 16);
}

__device__ __forceinline__ void gload_lds16(const void* g, void* l) {
    __builtin_amdgcn_global_load_lds((g_u32*)g, (l_u32*)l, 16, 0, 0);
}

// ---------------------------------------------------------------------------
// Kernel 1: embedding gather * sqrt(D) + sinusoidal positional encoding
// ---------------------------------------------------------------------------
__global__ __launch_bounds__(256) void embed_pe_kernel(
    const int* __restrict__ tokens, const float* __restrict__ emb,
    float* __restrict__ x)
{
    int idx = blockIdx.x * 256 + threadIdx.x;   // over B*S*D = 4M
    int d  = idx & (DD - 1);
    int bs = idx >> 9;                           // D = 512 = 2^9
    int s  = bs & (SS - 1);
    int tok = tokens[bs];
    float val = emb[(size_t)tok * DD + d] * 22.62741699796952f;  // sqrt(512)
    int i2 = d & ~1;
    float freq = expf((float)i2 * -0.017988946039015984f);  // -ln(10000)/512
    float ang = (float)s * freq;
    val += (d & 1) ? cosf(ang) : sinf(ang);
    x[idx] = val;
}

// ---------------------------------------------------------------------------
// Kernel 2: weight convert + transpose: W[K][N] fp32 -> Wt[N][K] bf16
// ---------------------------------------------------------------------------
__global__ __launch_bounds__(256) void wcvt_kernel(
    const float* __restrict__ W, short* __restrict__ Wt, int K, int N)
{
    __shared__ float tile[32][33];
    int n0 = blockIdx.x * 32, k0 = blockIdx.y * 32;
    int tx = threadIdx.x & 31, ty = threadIdx.x >> 5;   // 32 x 8
    #pragma unroll
    for (int i = 0; i < 4; ++i)
        tile[ty + i * 8][tx] = W[(size_t)(k0 + ty + i * 8) * N + n0 + tx];
    __syncthreads();
    #pragma unroll
    for (int i = 0; i < 4; ++i)
        Wt[(size_t)(n0 + ty + i * 8) * K + k0 + tx] = f2bf(tile[tx][ty + i * 8]);
}

// ---------------------------------------------------------------------------
// Kernel 3: LayerNorm (unbiased std, eps added to std, scalar alpha/bias).
// Reads fp32 x, writes bf16 (feeds MFMA GEMM A operand).
// ---------------------------------------------------------------------------
__global__ __launch_bounds__(256) void ln_kernel(
    const float* __restrict__ x, short* __restrict__ y,
    const float* __restrict__ alpha_p, const float* __restrict__ beta_p)
{
    int row = blockIdx.x;
    const float* xr = x + (size_t)row * DD;
    int t = threadIdx.x;
    float v0 = xr[t];
    float v1 = xr[t + 256];

    __shared__ float red[8];
    float s = v0 + v1;
    #pragma unroll
    for (int o = 32; o >= 1; o >>= 1) s += __shfl_xor(s, o, 64);
    int wid = t >> 6;
    if ((t & 63) == 0) red[wid] = s;
    __syncthreads();
    float mean = (red[0] + red[1] + red[2] + red[3]) * (1.0f / 512.0f);

    float d0 = v0 - mean, d1 = v1 - mean;
    float q = d0 * d0 + d1 * d1;
    #pragma unroll
    for (int o = 32; o >= 1; o >>= 1) q += __shfl_xor(q, o, 64);
    if ((t & 63) == 0) red[4 + wid] = q;
    __syncthreads();
    float var = (red[4] + red[5] + red[6] + red[7]) * (1.0f / 511.0f);
    float stdv = sqrtf(var);

    float alpha = alpha_p[0], beta = beta_p[0];
    float inv = alpha / (stdv + EPS);
    short* yr = y + (size_t)row * DD;
    yr[t]       = f2bf(d0 * inv + beta);
    yr[t + 256] = f2bf(d1 * inv + beta);
}

// ---------------------------------------------------------------------------
// Kernel 4: bf16 MFMA GEMM  C[M,N] = A[M,K] @ Wt[N,K]^T + bias
// m97 structure: 128x128 tile, BK=64, 4 waves (2x2 of 64x64), global_load_lds
// staging, 2-barrier K-loop, 32 MFMA / K-step / wave.
// A[M][K] bf16 row-major; Wt[N][K] bf16 row-major (pre-transposed weights).
// Output: bf16 (OUT_BF16) or fp32 (+optional fp32 residual R, optional ReLU).
// ---------------------------------------------------------------------------
template <bool RELU, bool RES, bool OUT_BF16>
__global__ __launch_bounds__(256) void gemm_mfma(
    const short* __restrict__ A, const short* __restrict__ Wt,
    const float* __restrict__ bias, const float* __restrict__ R,
    void* __restrict__ Cout, int M, int N, int K)
{
    __shared__ __align__(16) short As[128 * 64];   // [m][k]
    __shared__ __align__(16) short Bs[128 * 64];   // [n][k]

    const int t = threadIdx.x;
    const int w = t >> 6, l = t & 63;
    const int l15 = l & 15, l4 = l >> 4;
    const int wr = w >> 1, wc = w & 1;            // wave 2x2 grid

    const int m0 = blockIdx.y * 128, n0 = blockIdx.x * 128;

    f32x4 acc[4][4];
    #pragma unroll
    for (int mi = 0; mi < 4; ++mi)
        #pragma unroll
        for (int ni = 0; ni < 4; ++ni) acc[mi][ni] = (f32x4){0.f, 0.f, 0.f, 0.f};

    const int lrow = l >> 3;            // 0..7
    const int lcol = (l & 7) * 8;       // shorts (16B per lane)

    for (int k0 = 0; k0 < K; k0 += 64) {
        #pragma unroll
        for (int i = 0; i < 4; ++i) {
            int r0 = (w * 4 + i) * 8;   // 8-row chunk base (wave-uniform)
            gload_lds16(A  + (size_t)(m0 + r0 + lrow) * K + k0 + lcol, &As[r0 * 64]);
            gload_lds16(Wt + (size_t)(n0 + r0 + lrow) * K + k0 + lcol, &Bs[r0 * 64]);
        }
        __syncthreads();   // compiler emits vmcnt(0) drain before barrier

        #pragma unroll
        for (int ks = 0; ks < 2; ++ks) {
            bf16x8 af[4], bf_[4];
            #pragma unroll
            for (int mi = 0; mi < 4; ++mi)
                af[mi] = *(const bf16x8*)&As[(wr * 64 + mi * 16 + l15) * 64 + ks * 32 + l4 * 8];
            #pragma unroll
            for (int ni = 0; ni < 4; ++ni)
                bf_[ni] = *(const bf16x8*)&Bs[(wc * 64 + ni * 16 + l15) * 64 + ks * 32 + l4 * 8];
            #pragma unroll
            for (int mi = 0; mi < 4; ++mi)
                #pragma unroll
                for (int ni = 0; ni < 4; ++ni)
                    acc[mi][ni] = __builtin_amdgcn_mfma_f32_16x16x32_bf16(
                        af[mi], bf_[ni], acc[mi][ni], 0, 0, 0);
        }
        __syncthreads();
    }

    // epilogue: D[i][j]: j = l15, i = l4*4 + reg
    #pragma unroll
    for (int mi = 0; mi < 4; ++mi) {
        #pragma unroll
        for (int ni = 0; ni < 4; ++ni) {
            int col = n0 + wc * 64 + ni * 16 + l15;
            float bcol = bias[col];
            #pragma unroll
            for (int r = 0; r < 4; ++r) {
                int row = m0 + wr * 64 + mi * 16 + l4 * 4 + r;
                float c = acc[mi][ni][r] + bcol;
                if (RES)  c += R[(size_t)row * N + col];
                if (RELU) c = fmaxf(c, 0.0f);
                if (OUT_BF16) ((short*)Cout)[(size_t)row * N + col] = f2bf(c);
                else          ((float*)Cout)[(size_t)row * N + col] = c;
            }
        }
    }
}

// ---------------------------------------------------------------------------
// Kernel 5: MFMA bf16 flash attention (bf16 q/k/v in, bf16 out).
// Block = one (b,h) x 128 q-rows; 4 waves x 32 q-rows. K-tile = 64 keys.
// K staged [key][d], V staged transposed [d][key], both XOR-swizzled
// (short-index ^= (row&7)<<3) so b128 frag reads are conflict-free.
// ---------------------------------------------------------------------------
#define SWZ(row, col) (((row) * 64 + (col)) ^ (((row) & 7) << 3))

__global__ __launch_bounds__(256) void attn_mfma_kernel(
    const short* __restrict__ q, const short* __restrict__ k,
    const short* __restrict__ v, const int* __restrict__ mask,
    short* __restrict__ o)
{
    __shared__ __align__(16) short Ks[64 * 64];      // [key][d] swizzled
    __shared__ __align__(16) short Vt[64 * 64];      // [d][key] swizzled
    __shared__ __align__(16) short Ps[4][32 * 64];   // per-wave P [q][key] swizzled

    const int qt = blockIdx.x;               // 0..7
    const int bh = blockIdx.y;               // 0..63
    const int b = bh >> 3, h = bh & 7;

    const int t = threadIdx.x;
    const int w = t >> 6;
    const int l = t & 63;
    const int l15 = l & 15, l4 = l >> 4;

    const short* kb = k + ((size_t)b * SS) * DD + h * HD;
    const short* vb = v + ((size_t)b * SS) * DD + h * HD;
    const int*   mb = mask + (size_t)b * SS;
    const int qbase = qt * 128 + w * 32;

    // Q fragments (A-layout): [qsub][kstep]
    bf16x8 qf[2][2];
    #pragma unroll
    for (int qs = 0; qs < 2; ++qs)
        #pragma unroll
        for (int ks = 0; ks < 2; ++ks)
            qf[qs][ks] = *(const bf16x8*)(q + ((size_t)b * SS + qbase + qs * 16 + l15) * DD
                                          + h * HD + ks * 32 + l4 * 8);

    float m_run[2][4], l_run[2][4];
    f32x4 O[2][4];                           // [qsub][dsub]
    #pragma unroll
    for (int qs = 0; qs < 2; ++qs)
        #pragma unroll
        for (int r = 0; r < 4; ++r) { m_run[qs][r] = -1e30f; l_run[qs][r] = 0.0f; }
    #pragma unroll
    for (int qs = 0; qs < 2; ++qs)
        #pragma unroll
        for (int ds = 0; ds < 4; ++ds) O[qs][ds] = (f32x4){0.f, 0.f, 0.f, 0.f};

    short* Pw = Ps[w];
    const int srow = t >> 2;                 // key row 0..63
    const int scol = (t & 3) * 16;           // d base

    for (int kt = 0; kt < SS / 64; ++kt) {
        // ---- stage K [key][d] and V^T [d][key] ----
        {
            const short* kp = kb + (size_t)(kt * 64 + srow) * DD + scol;
            bf16x8 k0v = *(const bf16x8*)kp;
            bf16x8 k1v = *(const bf16x8*)(kp + 8);
            *(bf16x8*)&Ks[SWZ(srow, scol)]     = k0v;
            *(bf16x8*)&Ks[SWZ(srow, scol + 8)] = k1v;

            const short* vp = vb + (size_t)(kt * 64 + srow) * DD + scol;
            bf16x8 v0v = *(const bf16x8*)vp;
            bf16x8 v1v = *(const bf16x8*)(vp + 8);
            #pragma unroll
            for (int j = 0; j < 8; ++j) {
                Vt[SWZ(scol + j,     srow)] = v0v[j];
                Vt[SWZ(scol + 8 + j, srow)] = v1v[j];
            }
        }
        __syncthreads();

        // ---- S = Q @ K^T ----
        f32x4 S[2][4];
        #pragma unroll
        for (int qs = 0; qs < 2; ++qs)
            #pragma unroll
            for (int ku = 0; ku < 4; ++ku) S[qs][ku] = (f32x4){0.f, 0.f, 0.f, 0.f};
        #pragma unroll
        for (int ks = 0; ks < 2; ++ks) {
            bf16x8 kf[4];
            #pragma unroll
            for (int ku = 0; ku < 4; ++ku)
                kf[ku] = *(const bf16x8*)&Ks[SWZ(l15 + 16 * ku, ks * 32 + l4 * 8)];
            #pragma unroll
            for (int qs = 0; qs < 2; ++qs)
                #pragma unroll
                for (int ku = 0; ku < 4; ++ku)
                    S[qs][ku] = __builtin_amdgcn_mfma_f32_16x16x32_bf16(
                        qf[qs][ks], kf[ku], S[qs][ku], 0, 0, 0);
        }

        // ---- online softmax ----
        int mv[4];
        #pragma unroll
        for (int ku = 0; ku < 4; ++ku) mv[ku] = mb[kt * 64 + ku * 16 + l15];

        float p[2][4][4];
        #pragma unroll
        for (int qs = 0; qs < 2; ++qs)
            #pragma unroll
            for (int ku = 0; ku < 4; ++ku)
                #pragma unroll
                for (int r = 0; r < 4; ++r) {
                    float sv = S[qs][ku][r] * 0.125f;
                    p[qs][ku][r] = (mv[ku] == 0) ? -1e9f : sv;
                }

        #pragma unroll
        for (int qs = 0; qs < 2; ++qs)
            #pragma unroll
            for (int r = 0; r < 4; ++r) {
                float mx = fmaxf(fmaxf(p[qs][0][r], p[qs][1][r]),
                                 fmaxf(p[qs][2][r], p[qs][3][r]));
                mx = fmaxf(mx, __shfl_xor(mx, 1, 64));
                mx = fmaxf(mx, __shfl_xor(mx, 2, 64));
                mx = fmaxf(mx, __shfl_xor(mx, 4, 64));
                mx = fmaxf(mx, __shfl_xor(mx, 8, 64));
                float mnew = fmaxf(m_run[qs][r], mx);
                float sc_old = __expf(m_run[qs][r] - mnew);
                m_run[qs][r] = mnew;
                float ps = 0.0f;
                #pragma unroll
                for (int ku = 0; ku < 4; ++ku) {
                    float e = __expf(p[qs][ku][r] - mnew);
                    p[qs][ku][r] = e;
                    ps += e;
                }
                ps += __shfl_xor(ps, 1, 64);
                ps += __shfl_xor(ps, 2, 64);
                ps += __shfl_xor(ps, 4, 64);
                ps += __shfl_xor(ps, 8, 64);
                l_run[qs][r] = l_run[qs][r] * sc_old + ps;
                #pragma unroll
                for (int ds = 0; ds < 4; ++ds) O[qs][ds][r] *= sc_old;
            }

        // ---- P -> per-wave LDS (bf16, swizzled) ----
        #pragma unroll
        for (int qs = 0; qs < 2; ++qs)
            #pragma unroll
            for (int ku = 0; ku < 4; ++ku)
                #pragma unroll
                for (int r = 0; r < 4; ++r)
                    Pw[SWZ(qs * 16 + l4 * 4 + r, ku * 16 + l15)] = f2bf(p[qs][ku][r]);

        // ---- O += P @ V ----
        #pragma unroll
        for (int ks = 0; ks < 2; ++ks) {
            bf16x8 vf[4];
            #pragma unroll
            for (int ds = 0; ds < 4; ++ds)
                vf[ds] = *(const bf16x8*)&Vt[SWZ(l15 + 16 * ds, ks * 32 + l4 * 8)];
            #pragma unroll
            for (int qs = 0; qs < 2; ++qs) {
                bf16x8 pf = *(const bf16x8*)&Pw[SWZ(qs * 16 + l15, ks * 32 + l4 * 8)];
                #pragma unroll
                for (int ds = 0; ds < 4; ++ds)
                    O[qs][ds] = __builtin_amdgcn_mfma_f32_16x16x32_bf16(
                        pf, vf[ds], O[qs][ds], 0, 0, 0);
            }
        }
        __syncthreads();
    }

    // ---- epilogue: O / l_run -> bf16 ----
    #pragma unroll
    for (int qs = 0; qs < 2; ++qs)
        #pragma unroll
        for (int r = 0; r < 4; ++r) {
            float inv = 1.0f / l_run[qs][r];
            int qrow = qbase + qs * 16 + l4 * 4 + r;
            short* orow = o + ((size_t)b * SS + qrow) * DD + h * HD;
            #pragma unroll
            for (int ds = 0; ds < 4; ++ds)
                orow[ds * 16 + l15] = f2bf(O[qs][ds][r] * inv);
        }
}

// ---------------------------------------------------------------------------
// Host launcher
// ---------------------------------------------------------------------------
extern "C" void kernel_launch(void* const* d_in, const int* in_sizes, int n_in,
                              void* d_out, int out_size, void* d_ws, size_t ws_size,
                              hipStream_t stream)
{
    const int*   tokens = (const int*)  d_in[0];
    const int*   mask   = (const int*)  d_in[1];
    const float* emb    = (const float*)d_in[2];
    const float* Wq     = (const float*)d_in[3];
    const float* bq     = (const float*)d_in[4];
    const float* Wk     = (const float*)d_in[5];
    const float* bk     = (const float*)d_in[6];
    const float* Wv     = (const float*)d_in[7];
    const float* bv     = (const float*)d_in[8];
    const float* Wo     = (const float*)d_in[9];
    const float* bo     = (const float*)d_in[10];
    const float* W1     = (const float*)d_in[11];
    const float* b1     = (const float*)d_in[12];
    const float* W2     = (const float*)d_in[13];
    const float* b2     = (const float*)d_in[14];
    const float* ln_a1  = (const float*)d_in[15];
    const float* ln_b1  = (const float*)d_in[16];
    const float* ln_a2  = (const float*)d_in[17];
    const float* ln_b2  = (const float*)d_in[18];

    float* x = (float*)d_out;                 // residual stream fp32, in place

    // workspace layout (bytes)
    char* p = (char*)d_ws;
    const size_t ACT2 = (size_t)MM * DD * 2;  // 8 MB bf16 activation
    short* h   = (short*)p;                 p += ACT2;
    short* qb  = (short*)p;                 p += ACT2;
    short* kb  = (short*)p;                 p += ACT2;
    short* vb  = (short*)p;                 p += ACT2;
    short* ff  = (short*)p;                 p += (size_t)MM * FF * 2;   // 32 MB
    short* Wqt = (short*)p;                 p += (size_t)DD * DD * 2;
    short* Wkt = (short*)p;                 p += (size_t)DD * DD * 2;
    short* Wvt = (short*)p;                 p += (size_t)DD * DD * 2;
    short* Wot = (short*)p;                 p += (size_t)DD * DD * 2;
    short* W1t = (short*)p;                 p += (size_t)DD * FF * 2;
    short* W2t = (short*)p;                 p += (size_t)FF * DD * 2;

    embed_pe_kernel<<<(MM * DD) / 256, 256, 0, stream>>>(tokens, emb, x);

    // one-time weight convert+transpose (must run every call; cheap)
    wcvt_kernel<<<dim3(DD / 32, DD / 32), 256, 0, stream>>>(Wq, Wqt, DD, DD);
    wcvt_kernel<<<dim3(DD / 32, DD / 32), 256, 0, stream>>>(Wk, Wkt, DD, DD);
    wcvt_kernel<<<dim3(DD / 32, DD / 32), 256, 0, stream>>>(Wv, Wvt, DD, DD);
    wcvt_kernel<<<dim3(DD / 32, DD / 32), 256, 0, stream>>>(Wo, Wot, DD, DD);
    wcvt_kernel<<<dim3(FF / 32, DD / 32), 256, 0, stream>>>(W1, W1t, DD, FF);
    wcvt_kernel<<<dim3(DD / 32, FF / 32), 256, 0, stream>>>(W2, W2t, FF, DD);

    dim3 gD(DD / 128, MM / 128);    // N=512 GEMMs: 4 x 64
    dim3 gF(FF / 128, MM / 128);    // N=2048 GEMM: 16 x 64
    dim3 gA(SS / 128, BB * HH);     // attention: 8 x 64

    for (int layer = 0; layer < LL; ++layer) {
        // --- attention sublayer ---
        ln_kernel<<<MM, 256, 0, stream>>>(x, h, ln_a1, ln_b1);
        gemm_mfma<false, false, true><<<gD, 256, 0, stream>>>(h, Wqt, bq, nullptr, qb, MM, DD, DD);
        gemm_mfma<false, false, true><<<gD, 256, 0, stream>>>(h, Wkt, bk, nullptr, kb, MM, DD, DD);
        gemm_mfma<false, false, true><<<gD, 256, 0, stream>>>(h, Wvt, bv, nullptr, vb, MM, DD, DD);
        attn_mfma_kernel<<<gA, 256, 0, stream>>>(qb, kb, vb, mask, h);
        gemm_mfma<false, true, false><<<gD, 256, 0, stream>>>(h, Wot, bo, x, x, MM, DD, DD);

        // --- feed-forward sublayer ---
        ln_kernel<<<MM, 256, 0, stream>>>(x, h, ln_a2, ln_b2);
        gemm_mfma<true, false, true><<<gF, 256, 0, stream>>>(h, W1t, b1, nullptr, ff, MM, FF, DD);
        gemm_mfma<false, true, false><<<gD, 256, 0, stream>>>(ff, W2t, b2, x, x, MM, DD, FF);
    }
}

// Round 5
// 1407.072 us; speedup vs baseline: 10.2754x; 1.0581x over previous
//
#include <hip/hip_runtime.h>
#include <hip/hip_bf16.h>
#include <math.h>

// Problem constants
#define BB 8
#define SS 1024
#define DD 512
#define HH 8
#define FF 2048
#define LL 6
#define HD 64
#define MM (BB * SS)      // 8192 rows
#define EPS 1e-6f
#define QKVS 1536         // fused QKV row stride

typedef __attribute__((ext_vector_type(8))) short bf16x8;
typedef __attribute__((ext_vector_type(4))) float f32x4;

typedef __attribute__((address_space(1))) const unsigned int g_u32;
typedef __attribute__((address_space(3))) unsigned int l_u32;

__device__ __forceinline__ short f2bf(float f) {
    union { float f; unsigned u; } c; c.f = f;
    unsigned u = c.u;
    u += 0x7fff + ((u >> 16) & 1);   // RNE
    return (short)(u >> 16);
}

__device__ __forceinline__ void gload_lds16(const void* g, void* l) {
    __builtin_amdgcn_global_load_lds((g_u32*)g, (l_u32*)l, 16, 0, 0);
}

// ---------------------------------------------------------------------------
// Kernel 1: embedding gather * sqrt(D) + sinusoidal positional encoding
// ---------------------------------------------------------------------------
__global__ __launch_bounds__(256) void embed_pe_kernel(
    const int* __restrict__ tokens, const float* __restrict__ emb,
    float* __restrict__ x)
{
    int idx = blockIdx.x * 256 + threadIdx.x;   // over B*S*D = 4M
    int d  = idx & (DD - 1);
    int bs = idx >> 9;                           // D = 512 = 2^9
    int s  = bs & (SS - 1);
    int tok = tokens[bs];
    float val = emb[(size_t)tok * DD + d] * 22.62741699796952f;  // sqrt(512)
    int i2 = d & ~1;
    float freq = expf((float)i2 * -0.017988946039015984f);  // -ln(10000)/512
    float ang = (float)s * freq;
    val += (d & 1) ? cosf(ang) : sinf(ang);
    x[idx] = val;
}

// ---------------------------------------------------------------------------
// Kernel 2: weight convert + transpose: W[K][N] fp32 -> Wt[N][K] bf16
// ---------------------------------------------------------------------------
__global__ __launch_bounds__(256) void wcvt_kernel(
    const float* __restrict__ W, short* __restrict__ Wt, int K, int N)
{
    __shared__ float tile[32][33];
    int n0 = blockIdx.x * 32, k0 = blockIdx.y * 32;
    int tx = threadIdx.x & 31, ty = threadIdx.x >> 5;   // 32 x 8
    #pragma unroll
    for (int i = 0; i < 4; ++i)
        tile[ty + i * 8][tx] = W[(size_t)(k0 + ty + i * 8) * N + n0 + tx];
    __syncthreads();
    #pragma unroll
    for (int i = 0; i < 4; ++i)
        Wt[(size_t)(n0 + ty + i * 8) * K + k0 + tx] = f2bf(tile[tx][ty + i * 8]);
}

// bias concat: [bq | bk | bv] -> bqkv[1536]
__global__ __launch_bounds__(256) void bcat_kernel(
    const float* __restrict__ bq, const float* __restrict__ bk,
    const float* __restrict__ bv, float* __restrict__ out)
{
    int i = blockIdx.x * 256 + threadIdx.x;
    float v = (i < 512) ? bq[i] : (i < 1024 ? bk[i - 512] : bv[i - 1024]);
    out[i] = v;
}

// ---------------------------------------------------------------------------
// Kernel 3: LayerNorm (unbiased std, eps added to std, scalar alpha/bias).
// fp32 in -> bf16 out. 2 rows per block, float4 loads, short4 stores.
// ---------------------------------------------------------------------------
__global__ __launch_bounds__(256) void ln_kernel(
    const float* __restrict__ x, short* __restrict__ y,
    const float* __restrict__ alpha_p, const float* __restrict__ beta_p)
{
    int t = threadIdx.x;
    int half = t >> 7, i = t & 127;
    int row = blockIdx.x * 2 + half;
    const float* xr = x + (size_t)row * DD;
    float4 v = *(const float4*)(xr + i * 4);

    __shared__ float red[8];
    float s = v.x + v.y + v.z + v.w;
    #pragma unroll
    for (int o = 32; o >= 1; o >>= 1) s += __shfl_xor(s, o, 64);
    int wv = t >> 6;
    if ((t & 63) == 0) red[wv] = s;
    __syncthreads();
    float mean = (red[half * 2] + red[half * 2 + 1]) * (1.0f / 512.0f);

    float d0 = v.x - mean, d1 = v.y - mean, d2 = v.z - mean, d3 = v.w - mean;
    float q = d0 * d0 + d1 * d1 + d2 * d2 + d3 * d3;
    #pragma unroll
    for (int o = 32; o >= 1; o >>= 1) q += __shfl_xor(q, o, 64);
    if ((t & 63) == 0) red[4 + wv] = q;
    __syncthreads();
    float var = (red[4 + half * 2] + red[5 + half * 2]) * (1.0f / 511.0f);
    float stdv = sqrtf(var);

    float alpha = alpha_p[0], beta = beta_p[0];
    float inv = alpha / (stdv + EPS);
    short4 ov;
    ov.x = f2bf(d0 * inv + beta); ov.y = f2bf(d1 * inv + beta);
    ov.z = f2bf(d2 * inv + beta); ov.w = f2bf(d3 * inv + beta);
    *(short4*)(y + (size_t)row * DD + i * 4) = ov;
}

// ---------------------------------------------------------------------------
// Kernel 4: bf16 MFMA GEMM  C[M,N] = A[M,K] @ Wt[N,K]^T + bias
// m97 structure, BM=128, BK=64, 4 waves, global_load_lds staging.
// BN=128: waves 2x2, wave tile 64x64 (acc 4x4). Grid-rich shapes.
// BN=64:  waves 4x1, wave tile 32x64 (acc 2x4). For N=512 outputs (2 blk/CU).
// ---------------------------------------------------------------------------
template <int BN, bool RELU, bool RES, bool OUT_BF16>
__global__ __launch_bounds__(256) void gemm_mfma(
    const short* __restrict__ A, const short* __restrict__ Wt,
    const float* __restrict__ bias, const float* __restrict__ R,
    void* __restrict__ Cout, int M, int N, int K)
{
    __shared__ __align__(16) short As[128 * 64];   // [m][k]
    __shared__ __align__(16) short Bs[BN * 64];    // [n][k]

    constexpr int MI = (BN == 128) ? 4 : 2;
    constexpr int NI = 4;

    const int t = threadIdx.x;
    const int w = t >> 6, l = t & 63;
    const int l15 = l & 15, l4 = l >> 4;
    const int wrow = (BN == 128) ? (w >> 1) * 64 : w * 32;
    const int wcol = (BN == 128) ? (w & 1) * 64 : 0;

    const int m0 = blockIdx.y * 128, n0 = blockIdx.x * BN;

    f32x4 acc[MI][NI];
    #pragma unroll
    for (int mi = 0; mi < MI; ++mi)
        #pragma unroll
        for (int ni = 0; ni < NI; ++ni) acc[mi][ni] = (f32x4){0.f, 0.f, 0.f, 0.f};

    const int lrow = l >> 3;            // 0..7
    const int lcol = (l & 7) * 8;       // shorts (16B per lane)

    for (int k0 = 0; k0 < K; k0 += 64) {
        #pragma unroll
        for (int i = 0; i < 4; ++i) {   // A: 16 chunks of 8 rows
            int r0 = (w * 4 + i) * 8;
            gload_lds16(A + (size_t)(m0 + r0 + lrow) * K + k0 + lcol, &As[r0 * 64]);
        }
        #pragma unroll
        for (int i = 0; i < BN / 32; ++i) {  // B: BN/8 chunks
            int r0 = (w * (BN / 32) + i) * 8;
            gload_lds16(Wt + (size_t)(n0 + r0 + lrow) * K + k0 + lcol, &Bs[r0 * 64]);
        }
        __syncthreads();

        #pragma unroll
        for (int ks = 0; ks < 2; ++ks) {
            bf16x8 af[MI], bf_[NI];
            #pragma unroll
            for (int mi = 0; mi < MI; ++mi)
                af[mi] = *(const bf16x8*)&As[(wrow + mi * 16 + l15) * 64 + ks * 32 + l4 * 8];
            #pragma unroll
            for (int ni = 0; ni < NI; ++ni)
                bf_[ni] = *(const bf16x8*)&Bs[(wcol + ni * 16 + l15) * 64 + ks * 32 + l4 * 8];
            #pragma unroll
            for (int mi = 0; mi < MI; ++mi)
                #pragma unroll
                for (int ni = 0; ni < NI; ++ni)
                    acc[mi][ni] = __builtin_amdgcn_mfma_f32_16x16x32_bf16(
                        af[mi], bf_[ni], acc[mi][ni], 0, 0, 0);
        }
        __syncthreads();
    }

    #pragma unroll
    for (int mi = 0; mi < MI; ++mi) {
        #pragma unroll
        for (int ni = 0; ni < NI; ++ni) {
            int col = n0 + wcol + ni * 16 + l15;
            float bcol = bias[col];
            #pragma unroll
            for (int r = 0; r < 4; ++r) {
                int row = m0 + wrow + mi * 16 + l4 * 4 + r;
                float c = acc[mi][ni][r] + bcol;
                if (RES)  c += R[(size_t)row * N + col];
                if (RELU) c = fmaxf(c, 0.0f);
                if (OUT_BF16) ((short*)Cout)[(size_t)row * N + col] = f2bf(c);
                else          ((float*)Cout)[(size_t)row * N + col] = c;
            }
        }
    }
}

// ---------------------------------------------------------------------------
// Kernel 5: MFMA bf16 flash attention, reading fused QKV [M][1536] bf16.
// Block = one (b,h) x 128 q-rows; 8 waves x 16 q-rows (512 thr). KVBLK = 64.
// K staged [key][d], V staged transposed [d][key], XOR-swizzled; per-wave P.
// ---------------------------------------------------------------------------
#define SWZ(row, col) (((row) * 64 + (col)) ^ (((row) & 7) << 3))

__global__ __launch_bounds__(512, 4) void attn_mfma_kernel(
    const short* __restrict__ qkv, const int* __restrict__ mask,
    short* __restrict__ o)
{
    __shared__ __align__(16) short Ks[64 * 64];      // [key][d] swizzled
    __shared__ __align__(16) short Vt[64 * 64];      // [d][key] swizzled
    __shared__ __align__(16) short Ps[8][16 * 64];   // per-wave P [q][key] swizzled

    const int qt = blockIdx.x;               // 0..7
    const int bh = blockIdx.y;               // 0..63
    const int b = bh >> 3, h = bh & 7;

    const int t = threadIdx.x;
    const int w = t >> 6;                    // wave 0..7
    const int l = t & 63;
    const int l15 = l & 15, l4 = l >> 4;

    const short* kb = qkv + ((size_t)b * SS) * QKVS + 512 + h * HD;
    const short* vb = qkv + ((size_t)b * SS) * QKVS + 1024 + h * HD;
    const int*   mb = mask + (size_t)b * SS;
    const int qbase = qt * 128 + w * 16;     // this wave's 16 q rows

    // Q fragments (A-layout): [kstep]
    bf16x8 qf[2];
    #pragma unroll
    for (int ks = 0; ks < 2; ++ks)
        qf[ks] = *(const bf16x8*)(qkv + ((size_t)b * SS + qbase + l15) * QKVS
                                  + h * HD + ks * 32 + l4 * 8);

    float m_run[4], l_run[4];
    f32x4 O[4];                              // [dsub]
    #pragma unroll
    for (int r = 0; r < 4; ++r) { m_run[r] = -1e30f; l_run[r] = 0.0f; }
    #pragma unroll
    for (int ds = 0; ds < 4; ++ds) O[ds] = (f32x4){0.f, 0.f, 0.f, 0.f};

    short* Pw = Ps[w];
    const int srow = t >> 3;                 // key row 0..63
    const int scol = (t & 7) * 8;            // d base (8 shorts = 16B)

    for (int kt = 0; kt < SS / 64; ++kt) {
        // ---- stage K [key][d] and V^T [d][key] ----
        {
            bf16x8 kv = *(const bf16x8*)(kb + (size_t)(kt * 64 + srow) * QKVS + scol);
            *(bf16x8*)&Ks[SWZ(srow, scol)] = kv;
            bf16x8 vv = *(const bf16x8*)(vb + (size_t)(kt * 64 + srow) * QKVS + scol);
            #pragma unroll
            for (int j = 0; j < 8; ++j)
                Vt[SWZ(scol + j, srow)] = vv[j];
        }
        __syncthreads();

        // ---- S = Q @ K^T ----
        f32x4 S[4];
        #pragma unroll
        for (int ku = 0; ku < 4; ++ku) S[ku] = (f32x4){0.f, 0.f, 0.f, 0.f};
        #pragma unroll
        for (int ks = 0; ks < 2; ++ks) {
            bf16x8 kf[4];
            #pragma unroll
            for (int ku = 0; ku < 4; ++ku)
                kf[ku] = *(const bf16x8*)&Ks[SWZ(l15 + 16 * ku, ks * 32 + l4 * 8)];
            #pragma unroll
            for (int ku = 0; ku < 4; ++ku)
                S[ku] = __builtin_amdgcn_mfma_f32_16x16x32_bf16(
                    qf[ks], kf[ku], S[ku], 0, 0, 0);
        }

        // ---- online softmax ----
        int mv[4];
        #pragma unroll
        for (int ku = 0; ku < 4; ++ku) mv[ku] = mb[kt * 64 + ku * 16 + l15];

        float p[4][4];                        // [ksub][r]
        #pragma unroll
        for (int ku = 0; ku < 4; ++ku)
            #pragma unroll
            for (int r = 0; r < 4; ++r) {
                float sv = S[ku][r] * 0.125f;
                p[ku][r] = (mv[ku] == 0) ? -1e9f : sv;
            }

        #pragma unroll
        for (int r = 0; r < 4; ++r) {
            float mx = fmaxf(fmaxf(p[0][r], p[1][r]), fmaxf(p[2][r], p[3][r]));
            mx = fmaxf(mx, __shfl_xor(mx, 1, 64));
            mx = fmaxf(mx, __shfl_xor(mx, 2, 64));
            mx = fmaxf(mx, __shfl_xor(mx, 4, 64));
            mx = fmaxf(mx, __shfl_xor(mx, 8, 64));
            float mnew = fmaxf(m_run[r], mx);
            float sc_old = __expf(m_run[r] - mnew);
            m_run[r] = mnew;
            float ps = 0.0f;
            #pragma unroll
            for (int ku = 0; ku < 4; ++ku) {
                float e = __expf(p[ku][r] - mnew);
                p[ku][r] = e;
                ps += e;
            }
            ps += __shfl_xor(ps, 1, 64);
            ps += __shfl_xor(ps, 2, 64);
            ps += __shfl_xor(ps, 4, 64);
            ps += __shfl_xor(ps, 8, 64);
            l_run[r] = l_run[r] * sc_old + ps;
            #pragma unroll
            for (int ds = 0; ds < 4; ++ds) O[ds][r] *= sc_old;
        }

        // ---- P -> per-wave LDS (bf16, swizzled) ----
        #pragma unroll
        for (int ku = 0; ku < 4; ++ku)
            #pragma unroll
            for (int r = 0; r < 4; ++r)
                Pw[SWZ(l4 * 4 + r, ku * 16 + l15)] = f2bf(p[ku][r]);

        // ---- O += P @ V ----
        #pragma unroll
        for (int ks = 0; ks < 2; ++ks) {
            bf16x8 vf[4];
            #pragma unroll
            for (int ds = 0; ds < 4; ++ds)
                vf[ds] = *(const bf16x8*)&Vt[SWZ(l15 + 16 * ds, ks * 32 + l4 * 8)];
            bf16x8 pf = *(const bf16x8*)&Pw[SWZ(l15, ks * 32 + l4 * 8)];
            #pragma unroll
            for (int ds = 0; ds < 4; ++ds)
                O[ds] = __builtin_amdgcn_mfma_f32_16x16x32_bf16(
                    pf, vf[ds], O[ds], 0, 0, 0);
        }
        __syncthreads();   // before next tile overwrites Ks/Vt
    }

    // ---- epilogue: O / l_run -> bf16 ----
    #pragma unroll
    for (int r = 0; r < 4; ++r) {
        float inv = 1.0f / l_run[r];
        int qrow = qbase + l4 * 4 + r;
        short* orow = o + ((size_t)b * SS + qrow) * DD + h * HD;
        #pragma unroll
        for (int ds = 0; ds < 4; ++ds)
            orow[ds * 16 + l15] = f2bf(O[ds][r] * inv);
    }
}

// ---------------------------------------------------------------------------
// Host launcher
// ---------------------------------------------------------------------------
extern "C" void kernel_launch(void* const* d_in, const int* in_sizes, int n_in,
                              void* d_out, int out_size, void* d_ws, size_t ws_size,
                              hipStream_t stream)
{
    const int*   tokens = (const int*)  d_in[0];
    const int*   mask   = (const int*)  d_in[1];
    const float* emb    = (const float*)d_in[2];
    const float* Wq     = (const float*)d_in[3];
    const float* bq     = (const float*)d_in[4];
    const float* Wk     = (const float*)d_in[5];
    const float* bk     = (const float*)d_in[6];
    const float* Wv     = (const float*)d_in[7];
    const float* bv     = (const float*)d_in[8];
    const float* Wo     = (const float*)d_in[9];
    const float* bo     = (const float*)d_in[10];
    const float* W1     = (const float*)d_in[11];
    const float* b1     = (const float*)d_in[12];
    const float* W2     = (const float*)d_in[13];
    const float* b2     = (const float*)d_in[14];
    const float* ln_a1  = (const float*)d_in[15];
    const float* ln_b1  = (const float*)d_in[16];
    const float* ln_a2  = (const float*)d_in[17];
    const float* ln_b2  = (const float*)d_in[18];

    float* x = (float*)d_out;                 // residual stream fp32, in place

    // workspace layout (bytes)
    char* p = (char*)d_ws;
    short* qkv  = (short*)p;  p += (size_t)MM * QKVS * 2;    // 25.2 MB
    short* h    = (short*)p;  p += (size_t)MM * DD * 2;      // 8 MB
    short* ff   = (short*)p;  p += (size_t)MM * FF * 2;      // 32 MB
    short* Wqkvt= (short*)p;  p += (size_t)QKVS * DD * 2;    // 1.5 MB
    short* Wot  = (short*)p;  p += (size_t)DD * DD * 2;
    short* W1t  = (short*)p;  p += (size_t)FF * DD * 2;
    short* W2t  = (short*)p;  p += (size_t)DD * FF * 2;
    float* bqkv = (float*)p;  p += QKVS * 4;

    embed_pe_kernel<<<(MM * DD) / 256, 256, 0, stream>>>(tokens, emb, x);

    // one-time weight convert+transpose (runs every call; cheap)
    wcvt_kernel<<<dim3(DD / 32, DD / 32), 256, 0, stream>>>(Wq, Wqkvt,            DD, DD);
    wcvt_kernel<<<dim3(DD / 32, DD / 32), 256, 0, stream>>>(Wk, Wqkvt + 512*512,  DD, DD);
    wcvt_kernel<<<dim3(DD / 32, DD / 32), 256, 0, stream>>>(Wv, Wqkvt + 1024*512, DD, DD);
    wcvt_kernel<<<dim3(DD / 32, DD / 32), 256, 0, stream>>>(Wo, Wot, DD, DD);
    wcvt_kernel<<<dim3(FF / 32, DD / 32), 256, 0, stream>>>(W1, W1t, DD, FF);
    wcvt_kernel<<<dim3(DD / 32, FF / 32), 256, 0, stream>>>(W2, W2t, FF, DD);
    bcat_kernel<<<QKVS / 256, 256, 0, stream>>>(bq, bk, bv, bqkv);

    dim3 gQKV(QKVS / 128, MM / 128);   // 12 x 64 = 768 blocks
    dim3 gO  (DD / 64,    MM / 128);   // 8 x 64  = 512 blocks (BN=64)
    dim3 gF1 (FF / 128,   MM / 128);   // 16 x 64 = 1024 blocks
    dim3 gF2 (DD / 64,    MM / 128);   // 8 x 64  = 512 blocks (BN=64)
    dim3 gA  (SS / 128,   BB * HH);    // 8 x 64  = 512 blocks

    for (int layer = 0; layer < LL; ++layer) {
        // --- attention sublayer ---
        ln_kernel<<<MM / 2, 256, 0, stream>>>(x, h, ln_a1, ln_b1);
        gemm_mfma<128, false, false, true><<<gQKV, 256, 0, stream>>>(
            h, Wqkvt, bqkv, nullptr, qkv, MM, QKVS, DD);
        attn_mfma_kernel<<<gA, 512, 0, stream>>>(qkv, mask, h);
        gemm_mfma<64, false, true, false><<<gO, 256, 0, stream>>>(
            h, Wot, bo, x, x, MM, DD, DD);

        // --- feed-forward sublayer ---
        ln_kernel<<<MM / 2, 256, 0, stream>>>(x, h, ln_a2, ln_b2);
        gemm_mfma<128, true, false, true><<<gF1, 256, 0, stream>>>(
            h, W1t, b1, nullptr, ff, MM, FF, DD);
        gemm_mfma<64, false, true, false><<<gF2, 256, 0, stream>>>(
            ff, W2t, b2, x, x, MM, DD, FF);
    }
}